// Round 8
// baseline (541.878 us; speedup 1.0000x reference)
//
#include <hip/hip_runtime.h>
#include <cstdint>

typedef int v4i __attribute__((ext_vector_type(4)));

#define K_DIM 4096
#define BM 256
#define BN 256
#define BK 64
#define NT (K_DIM / BK)          // 64 K-tiles
#define BUFS 32768               // A 16KB + B 16KB per buffer
#define NBUF 4                   // 128 KiB LDS, stage-ahead 3, 2 tiles resident

// ---------------------------------------------------------------------------
// Kernel 0: fused prep. blocks [0, qrows): per-row int8 quantization of x.
// blocks [qrows, ...): pack int32 weight -> int8.
// ---------------------------------------------------------------------------
__global__ __launch_bounds__(256) void prep(
    const float* __restrict__ x, int8_t* __restrict__ q,
    float* __restrict__ scales,
    const int* __restrict__ w32, int8_t* __restrict__ w8,
    int qrows, int total16)
{
    const int b = blockIdx.x;
    const int t = threadIdx.x;
    if (b < qrows) {
        const float4* xr4 = reinterpret_cast<const float4*>(x + (size_t)b * K_DIM);
        float4 v[4];
        float m = 0.0f;
#pragma unroll
        for (int i = 0; i < 4; ++i) {
            v[i] = xr4[i * 256 + t];
            m = fmaxf(m, fmaxf(fmaxf(fabsf(v[i].x), fabsf(v[i].y)),
                               fmaxf(fabsf(v[i].z), fabsf(v[i].w))));
        }
#pragma unroll
        for (int off = 32; off >= 1; off >>= 1)
            m = fmaxf(m, __shfl_xor(m, off, 64));
        __shared__ float wmax[4];
        if ((t & 63) == 0) wmax[t >> 6] = m;
        __syncthreads();
        const float am = fmaxf(fmaxf(wmax[0], wmax[1]), fmaxf(wmax[2], wmax[3]));
        const float s  = fmaxf(am / 127.0f, 1e-8f);
        if (t == 0) scales[b] = s;
        int* qi = reinterpret_cast<int*>(q + (size_t)b * K_DIM);
#pragma unroll
        for (int i = 0; i < 4; ++i) {
            const float e[4] = {v[i].x, v[i].y, v[i].z, v[i].w};
            unsigned packed = 0;
#pragma unroll
            for (int j = 0; j < 4; ++j) {
                float r = rintf(e[j] / s);
                r = fminf(fmaxf(r, -127.0f), 127.0f);
                packed |= ((unsigned)((int)r & 0xff)) << (8 * j);
            }
            qi[i * 256 + t] = (int)packed;
        }
    } else {
        const int i = (b - qrows) * 256 + t;
        if (i >= total16) return;
        const v4i* src = reinterpret_cast<const v4i*>(w32) + i * 4;
        v4i out;
#pragma unroll
        for (int j = 0; j < 4; ++j) {
            const v4i vv = src[j];
            out[j] = (vv.x & 0xff) | ((vv.y & 0xff) << 8) |
                     ((vv.z & 0xff) << 16) | ((unsigned)(vv.w & 0xff) << 24);
        }
        reinterpret_cast<v4i*>(w8)[i] = out;
    }
}

// ---------------------------------------------------------------------------
// Kernel 2: int8 GEMM, 256x256 tile, 4 waves (2Mx2N), wave-tile 128x128,
// ONE wave per SIMD. Accumulator acc[8][8] (256 regs) FORCED INTO AGPRs via
// inline-asm v_mfma with "+a" constraint (R6 showed the builtin keeps it in
// VGPRs -> 470 MB scratch spill). Operands stay in VGPRs (~140).
// B-frags register-resident per K-tile (double-buffered Ba/Bb); A-frags via
// 4-deep ring, lead 2 phases; 1 GLDS chunk staged per phase (tile t+3);
// one barrier + counted vmcnt(8) per tile. Structure = R6 (refcheck'd).
//
// Residency invariant (per-wave in-order vmcnt): entering tile t, tiles t,t+1
// retired+visible; t+2's 8 loads in flight; during t stage t+3's 8. Boundary
// vmcnt(8) retires t+2's. bufn reads (B-next, phase-6/7 A-next) target t+1:
// resident. Stage at t overwrites buf[(t+3)&3]=buf[(t-1)&3], whose ds_reads
// were all value-consumed (lgkm-retired) before the t-1 -> t barrier.
// ---------------------------------------------------------------------------
__global__ __launch_bounds__(256, 1) void gemm_i8(
    const int8_t* __restrict__ A,   // [M][K] quantized activations
    const int8_t* __restrict__ B,   // [N][K] packed weight
    const float* __restrict__ sA,   // [M] per-row scales
    const float* __restrict__ wsc,  // [1] weight scale
    float* __restrict__ C,          // [M][N]
    int M, int N)
{
    __shared__ int8_t lds[NBUF * BUFS];   // 128 KiB

    const int t    = threadIdx.x;
    const int lane = t & 63;
    const int w    = t >> 6;        // 0..3
    const int wr   = w >> 1;        // 0..1 -> 128-row half
    const int wc   = w & 1;         // 0..1 -> 128-col half

    // T1: XCD-aware block swizzle (nwg = 512, divisible by 8)
    const int nwg = gridDim.x;
    int bid = blockIdx.x;
    if ((nwg & 7) == 0) bid = (bid & 7) * (nwg >> 3) + (bid >> 3);
    const int ntn  = N / BN;
    const int brow = (bid / ntn) * BM;
    const int bcol = (bid % ntn) * BN;

    // ---- staging: 8 chunks/thread/tile (A:0..3, B:4..7); linear LDS dest,
    // inverse-swizzled global source (0-conflict verified since R3) ----------
    const int8_t* gsrc[8];
    int ldst[8];
#pragma unroll
    for (int c = 0; c < 4; ++c) {
        const int idx  = c * 256 + t;
        const int row  = idx >> 2;                          // 0..255
        const int colq = (((idx & 3) ^ ((row >> 1) & 3)) << 4);
        gsrc[c]     = A + (size_t)(brow + row) * K_DIM + colq;
        ldst[c]     = idx * 16;
        gsrc[4 + c] = B + (size_t)(bcol + row) * K_DIM + colq;
        ldst[4 + c] = 16384 + idx * 16;
    }

#define GLDS(gp, off) \
    __builtin_amdgcn_global_load_lds( \
        (const __attribute__((address_space(1))) void*)(gp), \
        (__attribute__((address_space(3))) void*)(lds + (off)), 16, 0, 0)

    // ---- swizzled fragment offsets (frag stride 1024 = 16 rows * 64B) ------
    const int l15 = lane & 15;
    const unsigned swz = ((unsigned)((lane >> 4) ^ ((l15 >> 1) & 3))) << 4;
    const unsigned vA = (unsigned)((wr * 128 + l15) * 64) + swz;
    const unsigned vB = 16384u + (unsigned)((wc * 128 + l15) * 64) + swz;

    // ---- accumulator in AGPRs via inline-asm MFMA --------------------------
    v4i acc[8][8];
#pragma unroll
    for (int m = 0; m < 8; ++m)
#pragma unroll
        for (int n = 0; n < 8; ++n)
            acc[m][n] = (v4i){0, 0, 0, 0};

    v4i aR[4], Ba[8], Bb[8];

    // ---- prologue: stage tiles 0,1,2 (24 GLDS); retire tiles 0,1 -----------
#pragma unroll
    for (int c = 0; c < 8; ++c) GLDS(gsrc[c],            ldst[c]);
#pragma unroll
    for (int c = 0; c < 8; ++c) GLDS(gsrc[c] + BK,       BUFS + ldst[c]);
#pragma unroll
    for (int c = 0; c < 8; ++c) GLDS(gsrc[c] + 2 * BK, 2 * BUFS + ldst[c]);
    asm volatile("s_waitcnt vmcnt(8)" ::: "memory");
    __builtin_amdgcn_s_barrier();

    // preload tile 0: all 8 B-frags + A-frags 0,1
#pragma unroll
    for (int n = 0; n < 8; ++n) Ba[n] = *(const v4i*)(lds + vB + n * 1024);
    aR[0] = *(const v4i*)(lds + vA);
    aR[1] = *(const v4i*)(lds + vA + 1024);

    // AGPR-destination MFMA: D,C tied in AGPRs; A,B operands in VGPRs.
#define MFMA1(ACC, AV, BV) \
    asm("v_mfma_i32_16x16x64_i8 %0, %1, %2, %0" \
        : "+a"(ACC) : "v"(AV), "v"(BV))

#define MFMA8(P, BC) do { \
    MFMA1(acc[P][0], aR[(P)&3], BC[0]); \
    MFMA1(acc[P][1], aR[(P)&3], BC[1]); \
    MFMA1(acc[P][2], aR[(P)&3], BC[2]); \
    MFMA1(acc[P][3], aR[(P)&3], BC[3]); \
    MFMA1(acc[P][4], aR[(P)&3], BC[4]); \
    MFMA1(acc[P][5], aR[(P)&3], BC[5]); \
    MFMA1(acc[P][6], aR[(P)&3], BC[6]); \
    MFMA1(acc[P][7], aR[(P)&3], BC[7]); \
    } while (0)

    // phase P: A-ring read (lead 2), B-next read (lead 8), 1 stage chunk, 8 MFMA
#define PHASE(P, BC, BNX) do { \
    if ((P) <= 5) aR[((P)+2)&3] = *(const v4i*)(bufc + vA + ((P)+2) * 1024); \
    else if (notlast) aR[((P)+2)&3] = *(const v4i*)(bufn + vA + ((P)-6) * 1024); \
    if (notlast) BNX[(P)] = *(const v4i*)(bufn + vB + (P) * 1024); \
    if (more) GLDS(gsrc[(P)] + (size_t)T3 * BK, stoff + ldst[(P)]); \
    MFMA8(P, BC); \
    } while (0)

#define TILE_BODY(T, BC, BNX) do { \
    const int8_t* bufc = lds + cur * BUFS; \
    const int8_t* bufn = lds + ((cur + 1) & 3) * BUFS; \
    const unsigned stoff = (unsigned)(((cur + 3) & 3) * BUFS); \
    const bool more = (T) + 3 < NT; \
    const bool notlast = (T) + 1 < NT; \
    const int T3 = (T) + 3; \
    PHASE(0, BC, BNX); PHASE(1, BC, BNX); PHASE(2, BC, BNX); PHASE(3, BC, BNX); \
    PHASE(4, BC, BNX); PHASE(5, BC, BNX); PHASE(6, BC, BNX); PHASE(7, BC, BNX); \
    if (more)         asm volatile("s_waitcnt vmcnt(8)" ::: "memory"); \
    else              asm volatile("s_waitcnt vmcnt(0)" ::: "memory"); \
    if (notlast) __builtin_amdgcn_s_barrier(); \
    cur = (cur + 1) & 3; \
    } while (0)

    int cur = 0;
    for (int tt = 0; tt < NT; tt += 2) {
        TILE_BODY(tt,     Ba, Bb);   // compute with Ba, prefetch Bb
        TILE_BODY(tt + 1, Bb, Ba);   // compute with Bb, prefetch Ba
    }

    // ---- epilogue: C/D layout col = lane&15, row = (lane>>4)*4 + reg ------
    const float wsv = wsc[0];
#pragma unroll
    for (int m = 0; m < 8; ++m) {
        const int rbase = brow + wr * 128 + m * 16 + (lane >> 4) * 4;
        float sc[4];
#pragma unroll
        for (int j = 0; j < 4; ++j) sc[j] = sA[rbase + j] * wsv;
#pragma unroll
        for (int n = 0; n < 8; ++n) {
            const int col = bcol + wc * 128 + n * 16 + l15;
#pragma unroll
            for (int j = 0; j < 4; ++j)
                C[(size_t)(rbase + j) * N + col] = (float)acc[m][n][j] * sc[j];
        }
    }
#undef GLDS
#undef MFMA1
#undef MFMA8
#undef PHASE
#undef TILE_BODY
}

extern "C" void kernel_launch(void* const* d_in, const int* in_sizes, int n_in,
                              void* d_out, int out_size, void* d_ws, size_t ws_size,
                              hipStream_t stream) {
    const float* x      = (const float*)d_in[0];
    const int*   w32    = (const int*)d_in[1];     // int8 widened to int32
    const float* wscale = (const float*)d_in[2];
    float*       out    = (float*)d_out;

    const int M = in_sizes[0] / K_DIM;   // 8192
    const int N = in_sizes[1] / K_DIM;   // 4096

    int8_t* q      = (int8_t*)d_ws;
    float*  scales = (float*)((char*)d_ws + (size_t)M * K_DIM);
    int8_t* w8     = (int8_t*)((char*)d_ws + (size_t)M * K_DIM + (size_t)M * sizeof(float));

    const int total16 = (N * K_DIM) / 16;           // 1,048,576
    const int pblocks = (total16 + 255) / 256;      // 4096
    prep<<<M + pblocks, 256, 0, stream>>>(x, q, scales, w32, w8, M, total16);

    const int nblk = (M / BM) * (N / BN);           // 512
    gemm_i8<<<nblk, 256, 0, stream>>>(q, w8, scales, wscale, out, M, N);
}

// Round 9
// 271.783 us; speedup vs baseline: 1.9938x; 1.9938x over previous
//
#include <hip/hip_runtime.h>
#include <cstdint>

typedef int v4i __attribute__((ext_vector_type(4)));

#define K_DIM 4096
#define BM 256
#define BN 256
#define BK 64
#define NT (K_DIM / BK)          // 64 K-tiles
#define ATILE (BM * BK)          // 16 KiB A tile

// ---------------------------------------------------------------------------
// Kernel 0: fused prep. blocks [0, qrows): per-row int8 quantization of x.
// blocks [qrows, ...): pack int32 weight -> int8.
// ---------------------------------------------------------------------------
__global__ __launch_bounds__(256) void prep(
    const float* __restrict__ x, int8_t* __restrict__ q,
    float* __restrict__ scales,
    const int* __restrict__ w32, int8_t* __restrict__ w8,
    int qrows, int total16)
{
    const int b = blockIdx.x;
    const int t = threadIdx.x;
    if (b < qrows) {
        const float4* xr4 = reinterpret_cast<const float4*>(x + (size_t)b * K_DIM);
        float4 v[4];
        float m = 0.0f;
#pragma unroll
        for (int i = 0; i < 4; ++i) {
            v[i] = xr4[i * 256 + t];
            m = fmaxf(m, fmaxf(fmaxf(fabsf(v[i].x), fabsf(v[i].y)),
                               fmaxf(fabsf(v[i].z), fabsf(v[i].w))));
        }
#pragma unroll
        for (int off = 32; off >= 1; off >>= 1)
            m = fmaxf(m, __shfl_xor(m, off, 64));
        __shared__ float wmax[4];
        if ((t & 63) == 0) wmax[t >> 6] = m;
        __syncthreads();
        const float am = fmaxf(fmaxf(wmax[0], wmax[1]), fmaxf(wmax[2], wmax[3]));
        const float s  = fmaxf(am / 127.0f, 1e-8f);
        if (t == 0) scales[b] = s;
        int* qi = reinterpret_cast<int*>(q + (size_t)b * K_DIM);
#pragma unroll
        for (int i = 0; i < 4; ++i) {
            const float e[4] = {v[i].x, v[i].y, v[i].z, v[i].w};
            unsigned packed = 0;
#pragma unroll
            for (int j = 0; j < 4; ++j) {
                float r = rintf(e[j] / s);
                r = fminf(fmaxf(r, -127.0f), 127.0f);
                packed |= ((unsigned)((int)r & 0xff)) << (8 * j);
            }
            qi[i * 256 + t] = (int)packed;
        }
    } else {
        const int i = (b - qrows) * 256 + t;
        if (i >= total16) return;
        const v4i* src = reinterpret_cast<const v4i*>(w32) + i * 4;
        v4i out;
#pragma unroll
        for (int j = 0; j < 4; ++j) {
            const v4i vv = src[j];
            out[j] = (vv.x & 0xff) | ((vv.y & 0xff) << 8) |
                     ((vv.z & 0xff) << 16) | ((unsigned)(vv.w & 0xff) << 24);
        }
        reinterpret_cast<v4i*>(w8)[i] = out;
    }
}

// ---------------------------------------------------------------------------
// Kernel 1: int8 GEMM, 256x256 tile, 8 waves (2Mx4N), wave = 128x64.
// A: LDS-staged (GLDS, NBUF=2 ping-pong, 32 KiB). B: DIRECT global->VGPR
// (4 x dwordx4/wave/tile, lead-1 double-buffer Ba/Bb; weight is L2/L3-hot).
// LDS port/tile/CU: 64 KB reads + 16 KB writes (was 96+32) -> below MFMA.
// One vmcnt(0)+barrier per tile; all loads issued at TOP of body, so the
// full tile (~1300 cy of MFMA) hides their latency.
//
// Races: (1) GLDS A(t+1) writes buf[cur^1], whose old content A(t-1) was
// fully consumed before the t-1 -> t barrier (compiler waits lgkm before
// each MFMA use; MFMAs precede the barrier). GLDS issues after that
// barrier. (2) LOADB into BNX overwrites B(t-1), consumed by t-1's MFMAs
// earlier in this wave's own program order. (3) vmcnt(0) before the
// boundary barrier retires A(t+1)-GLDS and B(t+1) regardless of issue
// order — no counted-vmcnt ordering assumptions.
// ---------------------------------------------------------------------------
__global__ __launch_bounds__(512, 2) void gemm_i8(
    const int8_t* __restrict__ A,   // [M][K] quantized activations
    const int8_t* __restrict__ B,   // [N][K] packed weight
    const float* __restrict__ sA,   // [M] per-row scales
    const float* __restrict__ wsc,  // [1] weight scale
    float* __restrict__ C,          // [M][N]
    int M, int N)
{
    __shared__ int8_t lds[2 * ATILE];   // 32 KiB

    const int t    = threadIdx.x;
    const int lane = t & 63;
    const int w    = t >> 6;        // 0..7
    const int wr   = w >> 2;        // 0..1 -> 128-row half
    const int wc   = w & 3;         // 0..3 -> 64-col slice
    const int l15  = lane & 15;

    // T1: XCD-aware block swizzle (nwg = 512, divisible by 8)
    const int nwg = gridDim.x;
    int bid = blockIdx.x;
    if ((nwg & 7) == 0) bid = (bid & 7) * (nwg >> 3) + (bid >> 3);
    const int ntn  = N / BN;
    const int brow = (bid / ntn) * BM;
    const int bcol = (bid % ntn) * BN;

    // ---- A staging: 2 chunks/thread; linear LDS dest, inverse-swizzled
    // global source (0-conflict verified since R3) ---------------------------
    const int8_t* gsA[2];
    int ldA[2];
#pragma unroll
    for (int c = 0; c < 2; ++c) {
        const int idx = c * 512 + t;                       // 0..1023
        const int row = idx >> 2;                          // 0..255
        const int col = (((idx & 3) ^ ((row >> 1) & 3)) << 4);
        gsA[c] = A + (size_t)(brow + row) * K_DIM + col;
        ldA[c] = idx * 16;
    }

#define GLDS(gp, off) \
    __builtin_amdgcn_global_load_lds( \
        (const __attribute__((address_space(1))) void*)(gp), \
        (__attribute__((address_space(3))) void*)(lds + (off)), 16, 0, 0)

    // ---- B direct-load pointer: lane l15 -> row, lane>>4 -> 16B k-chunk ----
    const int8_t* gBrow = B + (size_t)(bcol + wc * 64 + l15) * K_DIM
                            + ((lane >> 4) << 4);

#define LOADB(BNX, tt) do { \
    BNX[0] = *(const v4i*)(gBrow + (size_t)(tt) * BK);                    \
    BNX[1] = *(const v4i*)(gBrow + 16u * K_DIM + (size_t)(tt) * BK);      \
    BNX[2] = *(const v4i*)(gBrow + 32u * K_DIM + (size_t)(tt) * BK);      \
    BNX[3] = *(const v4i*)(gBrow + 48u * K_DIM + (size_t)(tt) * BK);      \
    } while (0)

    // ---- swizzled A-fragment offsets (frag stride 1024 = 16 rows * 64 B) ---
    const unsigned swz = ((unsigned)((lane >> 4) ^ ((l15 >> 1) & 3))) << 4;
    const unsigned vA  = (unsigned)((wr * 128 + l15) * BK) + swz;

    v4i acc[8][4];
#pragma unroll
    for (int m = 0; m < 8; ++m)
#pragma unroll
        for (int n = 0; n < 4; ++n)
            acc[m][n] = (v4i){0, 0, 0, 0};

    v4i Ba[4], Bb[4];

    // ---- prologue: stage A(0), load B(0); drain; sync ----------------------
    GLDS(gsA[0], ldA[0]);
    GLDS(gsA[1], ldA[1]);
    LOADB(Ba, 0);
    asm volatile("s_waitcnt vmcnt(0)" ::: "memory");
    __builtin_amdgcn_s_barrier();

#define TILE_BODY(T, BC, BNX) do { \
    const int8_t* bufc = lds + cur * ATILE; \
    const int nxo = (cur ^ 1) * ATILE; \
    const bool notlast = (T) + 1 < NT; \
    if (notlast) { \
        GLDS(gsA[0] + (size_t)((T) + 1) * BK, nxo + ldA[0]); \
        GLDS(gsA[1] + (size_t)((T) + 1) * BK, nxo + ldA[1]); \
        LOADB(BNX, (T) + 1); \
    } \
    v4i af[8]; \
    af[0] = *(const v4i*)(bufc + vA);        \
    af[1] = *(const v4i*)(bufc + vA + 1024); \
    af[2] = *(const v4i*)(bufc + vA + 2048); \
    af[3] = *(const v4i*)(bufc + vA + 3072); \
    af[4] = *(const v4i*)(bufc + vA + 4096); \
    af[5] = *(const v4i*)(bufc + vA + 5120); \
    af[6] = *(const v4i*)(bufc + vA + 6144); \
    af[7] = *(const v4i*)(bufc + vA + 7168); \
    __builtin_amdgcn_s_setprio(1); \
    _Pragma("unroll") \
    for (int m = 0; m < 8; ++m) { \
        acc[m][0] = __builtin_amdgcn_mfma_i32_16x16x64_i8(af[m], BC[0], acc[m][0], 0,0,0); \
        acc[m][1] = __builtin_amdgcn_mfma_i32_16x16x64_i8(af[m], BC[1], acc[m][1], 0,0,0); \
        acc[m][2] = __builtin_amdgcn_mfma_i32_16x16x64_i8(af[m], BC[2], acc[m][2], 0,0,0); \
        acc[m][3] = __builtin_amdgcn_mfma_i32_16x16x64_i8(af[m], BC[3], acc[m][3], 0,0,0); \
    } \
    __builtin_amdgcn_s_setprio(0); \
    if (notlast) { \
        asm volatile("s_waitcnt vmcnt(0)" ::: "memory"); \
        __builtin_amdgcn_s_barrier(); \
    } \
    cur ^= 1; \
    } while (0)

    int cur = 0;
    for (int tt = 0; tt < NT; tt += 2) {
        TILE_BODY(tt,     Ba, Bb);   // compute with Ba, load B(t+1) into Bb
        TILE_BODY(tt + 1, Bb, Ba);   // compute with Bb, load into Ba
    }

    // ---- epilogue: C/D layout col = lane&15, row = (lane>>4)*4 + reg -------
    const float wsv = wsc[0];
#pragma unroll
    for (int m = 0; m < 8; ++m) {
        const int rbase = brow + wr * 128 + m * 16 + (lane >> 4) * 4;
        float sc[4];
#pragma unroll
        for (int j = 0; j < 4; ++j) sc[j] = sA[rbase + j] * wsv;
#pragma unroll
        for (int n = 0; n < 4; ++n) {
            const int col = bcol + wc * 64 + n * 16 + l15;
#pragma unroll
            for (int j = 0; j < 4; ++j)
                C[(size_t)(rbase + j) * N + col] = (float)acc[m][n][j] * sc[j];
        }
    }
#undef GLDS
#undef LOADB
#undef TILE_BODY
}

extern "C" void kernel_launch(void* const* d_in, const int* in_sizes, int n_in,
                              void* d_out, int out_size, void* d_ws, size_t ws_size,
                              hipStream_t stream) {
    const float* x      = (const float*)d_in[0];
    const int*   w32    = (const int*)d_in[1];     // int8 widened to int32
    const float* wscale = (const float*)d_in[2];
    float*       out    = (float*)d_out;

    const int M = in_sizes[0] / K_DIM;   // 8192
    const int N = in_sizes[1] / K_DIM;   // 4096

    int8_t* q      = (int8_t*)d_ws;
    float*  scales = (float*)((char*)d_ws + (size_t)M * K_DIM);
    int8_t* w8     = (int8_t*)((char*)d_ws + (size_t)M * K_DIM + (size_t)M * sizeof(float));

    const int total16 = (N * K_DIM) / 16;           // 1,048,576
    const int pblocks = (total16 + 255) / 256;      // 4096
    prep<<<M + pblocks, 256, 0, stream>>>(x, q, scales, w32, w8, M, total16);

    const int nblk = (M / BM) * (N / BN);           // 512
    gemm_i8<<<nblk, 512, 0, stream>>>(q, w8, scales, wscale, out, M, N);
}

// Round 10
// 202.696 us; speedup vs baseline: 2.6734x; 1.3408x over previous
//
#include <hip/hip_runtime.h>
#include <cstdint>

typedef int v4i  __attribute__((ext_vector_type(4)));
typedef int v16i __attribute__((ext_vector_type(16)));

#define K_DIM 4096
#define BM 256
#define BN 256
#define BK 128
#define NT (K_DIM / BK)          // 32 K-tiles
#define ATILE (BM * BK)          // 32 KiB per operand tile
#define BUFS (2 * ATILE)         // 64 KiB (A + B); NBUF=2 -> 128 KiB LDS

// ---------------------------------------------------------------------------
// Kernel 0: fused prep. blocks [0, qrows): per-row int8 quantization of x.
// blocks [qrows, ...): pack int32 weight -> int8.  (verified R7/R8)
// ---------------------------------------------------------------------------
__global__ __launch_bounds__(256) void prep(
    const float* __restrict__ x, int8_t* __restrict__ q,
    float* __restrict__ scales,
    const int* __restrict__ w32, int8_t* __restrict__ w8,
    int qrows, int total16)
{
    const int b = blockIdx.x;
    const int t = threadIdx.x;
    if (b < qrows) {
        const float4* xr4 = reinterpret_cast<const float4*>(x + (size_t)b * K_DIM);
        float4 v[4];
        float m = 0.0f;
#pragma unroll
        for (int i = 0; i < 4; ++i) {
            v[i] = xr4[i * 256 + t];
            m = fmaxf(m, fmaxf(fmaxf(fabsf(v[i].x), fabsf(v[i].y)),
                               fmaxf(fabsf(v[i].z), fabsf(v[i].w))));
        }
#pragma unroll
        for (int off = 32; off >= 1; off >>= 1)
            m = fmaxf(m, __shfl_xor(m, off, 64));
        __shared__ float wmax[4];
        if ((t & 63) == 0) wmax[t >> 6] = m;
        __syncthreads();
        const float am = fmaxf(fmaxf(wmax[0], wmax[1]), fmaxf(wmax[2], wmax[3]));
        const float s  = fmaxf(am / 127.0f, 1e-8f);
        if (t == 0) scales[b] = s;
        int* qi = reinterpret_cast<int*>(q + (size_t)b * K_DIM);
#pragma unroll
        for (int i = 0; i < 4; ++i) {
            const float e[4] = {v[i].x, v[i].y, v[i].z, v[i].w};
            unsigned packed = 0;
#pragma unroll
            for (int j = 0; j < 4; ++j) {
                float r = rintf(e[j] / s);
                r = fminf(fmaxf(r, -127.0f), 127.0f);
                packed |= ((unsigned)((int)r & 0xff)) << (8 * j);
            }
            qi[i * 256 + t] = (int)packed;
        }
    } else {
        const int i = (b - qrows) * 256 + t;
        if (i >= total16) return;
        const v4i* src = reinterpret_cast<const v4i*>(w32) + i * 4;
        v4i out;
#pragma unroll
        for (int j = 0; j < 4; ++j) {
            const v4i vv = src[j];
            out[j] = (vv.x & 0xff) | ((vv.y & 0xff) << 8) |
                     ((vv.z & 0xff) << 16) | ((unsigned)(vv.w & 0xff) << 24);
        }
        reinterpret_cast<v4i*>(w8)[i] = out;
    }
}

// ---------------------------------------------------------------------------
// Kernel 1: int8 GEMM. 256x256 tile, BK=128, NBUF=2 ping-pong (128 KiB LDS),
// 8 waves (2Mx4N), wave = 128x64 as 4x2 frags of mfma_i32_32x32x32_i8
// (half the MFMA instructions of 16x16x64 at +12% rate).
// ONE barrier + ONE vmcnt(0) per 128-K tile (1/4 the sync events of the
// BK=64 2-phase structure, which pinned at ~2768 cy per 64-K).
//
// LDS swizzle (G4, 128B rows are a 32-way conflict unswizzled):
//   byte = row*128 + ((chunk ^ (row&7))<<4), chunk = (ks<<1)|h, h=lane>>5.
//   Per-thread base has bits5-6 = (row>>1)&3, bit4 = h^(row&1); the
//   ks-dependent address is base ^ (ks<<5) (carry-free XOR on bits 5-6).
// Staging writes linear LDS with inverse-swizzled GLOBAL source (rule 21).
//
// Races: stage of tile t+1 targets buf[cur^1] = buf read during tile t-1,
// whose ds_reads were lgkm-retired (value-consumed by t-1's MFMAs) before
// the t-1 -> t barrier. vmcnt(0)+barrier at end of t makes t+1 resident
// before any wave reads it. No counted-vmcnt ordering assumptions.
// ---------------------------------------------------------------------------
__global__ __launch_bounds__(512, 2) void gemm_i8(
    const int8_t* __restrict__ A,   // [M][K] quantized activations
    const int8_t* __restrict__ B,   // [N][K] packed weight
    const float* __restrict__ sA,   // [M] per-row scales
    const float* __restrict__ wsc,  // [1] weight scale
    float* __restrict__ C,          // [M][N]
    int M, int N)
{
    __shared__ int8_t lds[2 * BUFS];   // 128 KiB

    const int t    = threadIdx.x;
    const int lane = t & 63;
    const int w    = t >> 6;        // 0..7
    const int wr   = w >> 2;        // 0..1 -> 128-row half
    const int wc   = w & 3;         // 0..3 -> 64-col slice
    const int l31  = lane & 31;
    const int h    = lane >> 5;     // 0..1 -> 16B k-half within K=32

    // T1: XCD-aware block swizzle (nwg = 512, divisible by 8)
    const int nwg = gridDim.x;
    int bid = blockIdx.x;
    if ((nwg & 7) == 0) bid = (bid & 7) * (nwg >> 3) + (bid >> 3);
    const int ntn  = N / BN;
    const int brow = (bid / ntn) * BM;
    const int bcol = (bid % ntn) * BN;

    // ---- staging: 8 chunks/thread/tile (A:0..3, B:4..7); linear LDS dest,
    // inverse-swizzled global source ------------------------------------------
    const int8_t* gsrc[8];
    int ldst[8];
#pragma unroll
    for (int c = 0; c < 4; ++c) {
        const int idx  = c * 512 + t;                 // 0..2047
        const int row  = idx >> 3;                    // 0..255
        const int scol = ((idx & 7) ^ (row & 7)) << 4;
        gsrc[c]     = A + (size_t)(brow + row) * K_DIM + scol;
        ldst[c]     = idx * 16;
        gsrc[4 + c] = B + (size_t)(bcol + row) * K_DIM + scol;
        ldst[4 + c] = ATILE + idx * 16;
    }

#define GLDS(gp, off) \
    __builtin_amdgcn_global_load_lds( \
        (const __attribute__((address_space(1))) void*)(gp), \
        (__attribute__((address_space(3))) void*)(lds + (off)), 16, 0, 0)

    // ---- swizzled fragment base addresses ----------------------------------
    unsigned baseA[4], baseB[2];
#pragma unroll
    for (int mf = 0; mf < 4; ++mf) {
        const int row = wr * 128 + mf * 32 + l31;
        const int q   = row & 7;
        baseA[mf] = (unsigned)(row * BK) + (unsigned)((h ^ (q & 1)) << 4)
                  + (unsigned)((q >> 1) << 5);
    }
#pragma unroll
    for (int nf = 0; nf < 2; ++nf) {
        const int row = wc * 64 + nf * 32 + l31;
        const int q   = row & 7;
        baseB[nf] = (unsigned)ATILE + (unsigned)(row * BK)
                  + (unsigned)((h ^ (q & 1)) << 4) + (unsigned)((q >> 1) << 5);
    }

    v16i acc[4][2];
#pragma unroll
    for (int mf = 0; mf < 4; ++mf)
#pragma unroll
        for (int nf = 0; nf < 2; ++nf)
#pragma unroll
            for (int r = 0; r < 16; ++r)
                acc[mf][nf][r] = 0;

    // ---- prologue: stage tile 0 into buf0; drain; sync ---------------------
#pragma unroll
    for (int c = 0; c < 8; ++c) GLDS(gsrc[c], ldst[c]);
    asm volatile("s_waitcnt vmcnt(0)" ::: "memory");
    __builtin_amdgcn_s_barrier();

    int cur = 0;
    for (int tt = 0; tt < NT; ++tt) {
        const int8_t* bufc = lds + cur * BUFS;
        const int nxo = (cur ^ 1) * BUFS;
        const bool notlast = tt + 1 < NT;

        // stage next tile (async; whole tile of compute hides the latency)
        if (notlast) {
#pragma unroll
            for (int c = 0; c < 8; ++c)
                GLDS(gsrc[c] + (size_t)(tt + 1) * BK, nxo + ldst[c]);
        }

        __builtin_amdgcn_s_setprio(1);
#pragma unroll
        for (int ks = 0; ks < 4; ++ks) {
            const unsigned kx = (unsigned)(ks << 5);
            v4i af[4], bf[2];
#pragma unroll
            for (int mf = 0; mf < 4; ++mf)
                af[mf] = *(const v4i*)(bufc + (baseA[mf] ^ kx));
#pragma unroll
            for (int nf = 0; nf < 2; ++nf)
                bf[nf] = *(const v4i*)(bufc + (baseB[nf] ^ kx));
#pragma unroll
            for (int mf = 0; mf < 4; ++mf)
#pragma unroll
                for (int nf = 0; nf < 2; ++nf)
                    acc[mf][nf] = __builtin_amdgcn_mfma_i32_32x32x32_i8(
                        af[mf], bf[nf], acc[mf][nf], 0, 0, 0);
        }
        __builtin_amdgcn_s_setprio(0);

        if (notlast) {
            asm volatile("s_waitcnt vmcnt(0)" ::: "memory");
            __builtin_amdgcn_s_barrier();
        }
        cur ^= 1;
    }

    // ---- epilogue: 32x32 C/D layout (m74/m101 verified):
    //      col = lane&31, row = (reg&3) + 8*(reg>>2) + 4*(lane>>5) -----------
    const float wsv = wsc[0];
#pragma unroll
    for (int mf = 0; mf < 4; ++mf) {
        const int rb = brow + wr * 128 + mf * 32 + 4 * h;
#pragma unroll
        for (int g = 0; g < 4; ++g) {
#pragma unroll
            for (int r = 0; r < 4; ++r) {
                const int row = rb + 8 * g + r;
                const float sc = sA[row] * wsv;
#pragma unroll
                for (int nf = 0; nf < 2; ++nf) {
                    const int col = bcol + wc * 64 + nf * 32 + l31;
                    C[(size_t)row * N + col] = (float)acc[mf][nf][4 * g + r] * sc;
                }
            }
        }
    }
#undef GLDS
}

extern "C" void kernel_launch(void* const* d_in, const int* in_sizes, int n_in,
                              void* d_out, int out_size, void* d_ws, size_t ws_size,
                              hipStream_t stream) {
    const float* x      = (const float*)d_in[0];
    const int*   w32    = (const int*)d_in[1];     // int8 widened to int32
    const float* wscale = (const float*)d_in[2];
    float*       out    = (float*)d_out;

    const int M = in_sizes[0] / K_DIM;   // 8192
    const int N = in_sizes[1] / K_DIM;   // 4096

    int8_t* q      = (int8_t*)d_ws;
    float*  scales = (float*)((char*)d_ws + (size_t)M * K_DIM);
    int8_t* w8     = (int8_t*)((char*)d_ws + (size_t)M * K_DIM + (size_t)M * sizeof(float));

    const int total16 = (N * K_DIM) / 16;           // 1,048,576
    const int pblocks = (total16 + 255) / 256;      // 4096
    prep<<<M + pblocks, 256, 0, stream>>>(x, q, scales, w32, w8, M, total16);

    const int nblk = (M / BM) * (N / BN);           // 512
    gemm_i8<<<nblk, 512, 0, stream>>>(q, w8, scales, wscale, out, M, N);
}